// Round 15
// baseline (396.093 us; speedup 1.0000x reference)
//
#include <hip/hip_runtime.h>
#include <math.h>

#define N_NODES 100000
#define N_EDGES 600000
#define N_GRAPHS 512
#define D 128
#define SCAN_BS 1024
#define SCAN_NBC ((N_NODES + SCAN_BS - 1) / SCAN_BS)   // 98
#define NPART 8
#define PART_SZ (N_NODES / NPART)                      // 12500
#define E4 (N_EDGES / 4)                               // 150000
#define SPLIT_B 12500                                  // (N*D/4)/256
#define DBINS 64
#define DNB2 SCAN_NBC                                  // 98 chunks of 1024 nodes

typedef unsigned short u16;
typedef __attribute__((ext_vector_type(8))) short short8;
typedef __attribute__((ext_vector_type(4))) float f32x4;

__device__ __forceinline__ u16 f2bf(float f) {
    unsigned int u = __float_as_uint(f);
    u += 0x7FFFu + ((u >> 16) & 1u);
    return (u16)(u >> 16);
}
__device__ __forceinline__ float bf2f(u16 h) {
    return __uint_as_float(((unsigned int)h) << 16);
}
// fp32 -> (hi bf16 bits, lo bf16 bits) in low 16 of each
__device__ __forceinline__ void split2(float f, unsigned int& h16, unsigned int& l16) {
    unsigned int u = __float_as_uint(f);
    unsigned int hb = (u + (0x7FFFu + ((u >> 16) & 1u))) & 0xffff0000u;
    float lo = f - __uint_as_float(hb);
    unsigned int ul = __float_as_uint(lo);
    h16 = hb >> 16;
    l16 = (ul + (0x7FFFu + ((ul >> 16) & 1u))) >> 16;
}

// ---------------- zero helper ----------------
__global__ __launch_bounds__(256) void zero_i_kernel(int* __restrict__ p, int n) {
    int i = blockIdx.x * 256 + threadIdx.x;
    if (i < n) p[i] = 0;
}

// ---------------- R13 launch fusion (kept) ----------------
// histprep = hist U prep; scan1d = scan1 + degree-histogram; scan3d = scan3 U
// per-bin scan; filld = fill U dscatter. Sort binned in 98 chunks of 1024.

// ---- histprep: [0,EB) edge histogram; [EB,..) split-x + pack W ----
__global__ __launch_bounds__(256) void histprep_kernel(const int* __restrict__ dst,
                                                       int* __restrict__ deg,
                                                       const float* __restrict__ x,
                                                       u16* __restrict__ Hhi,
                                                       u16* __restrict__ Hlo,
                                                       const float* __restrict__ Wl1, const float* __restrict__ Wr1,
                                                       const float* __restrict__ Wl2, const float* __restrict__ Wr2,
                                                       const float* __restrict__ Wl3, const float* __restrict__ Wr3,
                                                       u16* __restrict__ wph, u16* __restrict__ wpl,
                                                       int EB) {
    if ((int)blockIdx.x < EB) {
        int e = blockIdx.x * 256 + threadIdx.x;
        if (e < N_EDGES) atomicAdd(&deg[dst[e]], 1);
        return;
    }
    const int pbid = blockIdx.x - EB;
    if (pbid < SPLIT_B) {
        const int i = pbid * 256 + threadIdx.x;   // 4 elems/thread
        const float4 v = ((const float4*)x)[i];
        unsigned int h0, l0, h1, l1, h2, l2, h3, l3;
        split2(v.x, h0, l0); split2(v.y, h1, l1);
        split2(v.z, h2, l2); split2(v.w, h3, l3);
        uint2 oh, ol;
        oh.x = h0 | (h1 << 16); oh.y = h2 | (h3 << 16);
        ol.x = l0 | (l1 << 16); ol.y = l2 | (l3 << 16);
        ((uint2*)Hhi)[i] = oh;
        ((uint2*)Hlo)[i] = ol;
    } else {
        const int b = (pbid - SPLIT_B) * 4 + (threadIdx.x >> 6);  // 0..191
        const int lane = threadIdx.x & 63;
        const int layer = b >> 6;
        const int t = b & 63;
        const float* Wl = (layer == 0) ? Wl1 : (layer == 1) ? Wl2 : Wl3;
        const float* Wr = (layer == 0) ? Wr1 : (layer == 1) ? Wr2 : Wr3;
        const int nt = t >> 3, kt = t & 7;
        const int n = nt * 16 + (lane & 15);
        const int k0 = kt * 32 + (lane >> 4) * 8;
        const size_t base = (size_t)layer * 32768 + (size_t)(t * 64 + lane) * 8;
        #pragma unroll
        for (int j = 0; j < 8; ++j) {
            const int k = k0 + j;
            const float w = (k < 128) ? Wl[k * 128 + n] : Wr[(k - 128) * 128 + n];
            const u16 h = f2bf(w);
            wph[base + j] = h;
            wpl[base + j] = f2bf(w - bf2f(h));
        }
    }
}

// ---- scan1d: node-degree block scan (rowptr part 1) + degree histogram ----
__global__ __launch_bounds__(1024) void scan1d_kernel(const int* __restrict__ deg,
                                                      int* __restrict__ excl,
                                                      int* __restrict__ blocksum,
                                                      int* __restrict__ histT,
                                                      int* __restrict__ bintot) {
    __shared__ int buf[2][SCAN_BS];
    __shared__ int h[DBINS];
    const int t = threadIdx.x;
    const int gid = blockIdx.x * SCAN_BS + t;
    int v = (gid < N_NODES) ? deg[gid] : 0;
    if (t < DBINS) h[t] = 0;
    buf[0][t] = v;
    __syncthreads();
    if (gid < N_NODES) atomicAdd(&h[63 - min(v, 63)], 1);   // descending-degree bin
    int pi = 0;
    for (int off = 1; off < SCAN_BS; off <<= 1) {
        int val = buf[pi][t];
        if (t >= off) val += buf[pi][t - off];
        buf[pi ^ 1][t] = val;
        pi ^= 1;
        __syncthreads();
    }
    int incl = buf[pi][t];
    if (gid < N_NODES) excl[gid] = incl - v;
    if (t == SCAN_BS - 1) blocksum[blockIdx.x] = incl;
    if (t < DBINS) {
        histT[t * DNB2 + blockIdx.x] = h[t];
        if (h[t] > 0) atomicAdd(&bintot[t], h[t]);
    }
}

// ---- scan3d: [0,NB) rowptr finalize; [NB,NB+64) per-bin offset scan ----
__global__ __launch_bounds__(256) void scan3d_kernel(const int* __restrict__ excl,
                                                     const int* __restrict__ blocksum,
                                                     int* __restrict__ rowptr,
                                                     const int* __restrict__ bintot,
                                                     int* __restrict__ histT,
                                                     int NB) {
    const int t = threadIdx.x;
    if ((int)blockIdx.x < NB) {
        __shared__ int buf[2][128];
        if (t < 128) buf[0][t] = (t < SCAN_NBC) ? blocksum[t] : 0;
        __syncthreads();
        int pi = 0;
        for (int off = 1; off < 128; off <<= 1) {
            if (t < 128) {
                int val = buf[pi][t];
                if (t >= off) val += buf[pi][t - off];
                buf[pi ^ 1][t] = val;
            }
            pi ^= 1;
            __syncthreads();
        }
        const int i = blockIdx.x * 256 + t;
        if (i < N_NODES) {
            const int j = i / SCAN_BS;
            const int pref = (j == 0) ? 0 : buf[pi][j - 1];
            rowptr[i] = excl[i] + pref;
        }
        if (i == 0) rowptr[N_NODES] = N_EDGES;
    } else {
        // per-bin exclusive scan of histT[b][0..DNB2) + global bin base
        __shared__ int buf[2][128];
        __shared__ int base;
        const int b = blockIdx.x - NB;
        if (t == 0) {
            int s = 0;
            for (int j = 0; j < b; ++j) s += bintot[j];
            base = s;
        }
        int v = 0;
        if (t < 128) {
            v = (t < DNB2) ? histT[b * DNB2 + t] : 0;
            buf[0][t] = v;
        }
        __syncthreads();
        int pi = 0;
        for (int off = 1; off < 128; off <<= 1) {
            if (t < 128) {
                int val = buf[pi][t];
                if (t >= off) val += buf[pi][t - off];
                buf[pi ^ 1][t] = val;
            }
            pi ^= 1;
            __syncthreads();
        }
        if (t < DNB2) histT[b * DNB2 + t] = base + buf[pi][t] - v;
    }
}

// ---- filld: [0,EPB) CSR fill (dst-range partitioned, R2 scatter-locality
// win); [EPB,EPB+DNB2) degree-sort scatter (1024 nodes/block) ----
__global__ __launch_bounds__(256) void filld_kernel(const int* __restrict__ src,
                                                    const int* __restrict__ dst,
                                                    const int* __restrict__ rowptr,
                                                    int* __restrict__ fill,
                                                    int* __restrict__ csr_src,
                                                    const int* __restrict__ deg,
                                                    const int* __restrict__ offs,
                                                    int* __restrict__ perm,
                                                    int EPB) {
    if ((int)blockIdx.x < EPB) {
        const int lo = (blockIdx.x & (NPART - 1)) * PART_SZ;
        const int i4 = (blockIdx.x >> 3) * 256 + threadIdx.x;
        if (i4 >= E4) return;
        const int4 d4 = ((const int4*)dst)[i4];
        const int4 s4 = ((const int4*)src)[i4];
        if ((unsigned)(d4.x - lo) < (unsigned)PART_SZ) {
            int pos = rowptr[d4.x] + atomicAdd(&fill[d4.x], 1);
            csr_src[pos] = s4.x;
        }
        if ((unsigned)(d4.y - lo) < (unsigned)PART_SZ) {
            int pos = rowptr[d4.y] + atomicAdd(&fill[d4.y], 1);
            csr_src[pos] = s4.y;
        }
        if ((unsigned)(d4.z - lo) < (unsigned)PART_SZ) {
            int pos = rowptr[d4.z] + atomicAdd(&fill[d4.z], 1);
            csr_src[pos] = s4.z;
        }
        if ((unsigned)(d4.w - lo) < (unsigned)PART_SZ) {
            int pos = rowptr[d4.w] + atomicAdd(&fill[d4.w], 1);
            csr_src[pos] = s4.w;
        }
    } else {
        __shared__ int c[DBINS];
        const int t = threadIdx.x;
        const int chunk = blockIdx.x - EPB;
        if (t < DBINS) c[t] = 0;
        __syncthreads();
        #pragma unroll
        for (int k = 0; k < 4; ++k) {
            const int i = chunk * 1024 + k * 256 + t;
            if (i < N_NODES) {
                const int b = 63 - min(deg[i], 63);
                const int r = atomicAdd(&c[b], 1);
                perm[offs[b * DNB2 + chunk] + r] = i;
            }
        }
    }
}

// ---------------- FUSED agg + MFMA GEMM (degree-sorted rows, BARRIER-FREE) ----------------
// h' = relu([mean_nbr(INhi) | IN] @ [Wl;Wr] + b), OUT != IN (ping-pong).
// R15 = R14 with the W-fragment indexing FIXED: col-tile Q occupies 4096 u16
// per plane (wprep: base=(t*64+lane)*8, nt=t>>3 -> tile base Q*4096, fragment
// at + kt*512 + lane*8). R14 used Q*8192 (byte stride confused with u16
// stride) -> tiles Q>=1 read wrong data, absmax 0.027.
// Structure (R14 theory, untested until now): W staging pipeline deleted.
// R13 counters (MfmaUtil 9%, VALU 19%, HBM 29% -- nothing saturated) convict
// the 16-barrier lockstep. B-fragments load directly from global: W is
// L2-resident (128 KB/layer), access is 1 KB fully-coalesced per wave-load.
// ZERO inter-wave synchronization (epilogue bounce per-wave-private 2 KB,
// lgkmcnt-ordered only): gather/MFMA/epilogue waves overlap freely. LDS 16 KB.
// Rows in perm order (descending degree = LPT, R11). Math order identical to
// R13 -> bit-identical output.
// Layer 3: rowdot[perm[lg]] = sum_col relu(.)*Wro[col] (no h' write).
__global__ __launch_bounds__(512, 4) void gemm_kernel(const u16* __restrict__ INhi,
                                                      const u16* __restrict__ INlo,
                                                      const int* __restrict__ rowptr,
                                                      const int* __restrict__ csr_src,
                                                      const int* __restrict__ perm,
                                                      const u16* __restrict__ Wph,
                                                      const u16* __restrict__ Wpl,
                                                      const float* __restrict__ bias,
                                                      u16* __restrict__ OHhi,
                                                      u16* __restrict__ OHlo,
                                                      const float* __restrict__ Wro,
                                                      float* rowdot) {
    __shared__ uint4 ldsB[1024];   // 16 KB: per-wave 2 KB epilogue bounce
    const int t = threadIdx.x;
    const int lane = t & 63;
    const int wv = t >> 6;
    const int m0 = blockIdx.x * 128 + wv * 16;
    const int gid = m0 + (lane & 15);            // logical row slot
    const int ko = (lane >> 4) * 8;

    int prow = 0, beg = 0, deg = 0;
    if (gid < N_NODES) {
        prow = perm[gid];
        beg = rowptr[prow];
        deg = rowptr[prow + 1] - beg;
    }
    const int rm = prow;                         // 0 for invalid slots (safe)

    // root A fragments: latency hides under the gather
    short8 ah[4], al[4];
    #pragma unroll
    for (int kt = 0; kt < 4; ++kt) {
        ah[kt] = *(const short8*)(INhi + (size_t)rm * D + kt * 32 + ko);
        al[kt] = *(const short8*)(INlo + (size_t)rm * D + kt * 32 + ko);
    }

    // ---- fused aggregation (R6 form): mean of neighbor rows, 32 cols/lane ----
    float ac[4][8];
    #pragma unroll
    for (int kt = 0; kt < 4; ++kt) {
        #pragma unroll
        for (int j = 0; j < 8; ++j) ac[kt][j] = 0.f;
    }
    int s_cur = (deg > 0) ? csr_src[beg] : 0;
    for (int n = 0; __any(n < deg); ++n) {
        const bool act = n < deg;
        const int s_nxt = (n + 1 < deg) ? csr_src[beg + n + 1] : 0;
        if (act) {
            const size_t rb = (size_t)s_cur * D + ko;
            #pragma unroll
            for (int kt = 0; kt < 4; ++kt) {
                const uint4 v = *(const uint4*)(INhi + rb + kt * 32);
                ac[kt][0] += __uint_as_float(v.x << 16);
                ac[kt][1] += __uint_as_float(v.x & 0xffff0000u);
                ac[kt][2] += __uint_as_float(v.y << 16);
                ac[kt][3] += __uint_as_float(v.y & 0xffff0000u);
                ac[kt][4] += __uint_as_float(v.z << 16);
                ac[kt][5] += __uint_as_float(v.z & 0xffff0000u);
                ac[kt][6] += __uint_as_float(v.w << 16);
                ac[kt][7] += __uint_as_float(v.w & 0xffff0000u);
            }
        }
        s_cur = s_nxt;
    }
    const float inv = 1.0f / (float)max(deg, 1);
    short8 am[4];
    #pragma unroll
    for (int kt = 0; kt < 4; ++kt) {
        uint4 u;
        u.x = (unsigned)f2bf(ac[kt][0] * inv) | ((unsigned)f2bf(ac[kt][1] * inv) << 16);
        u.y = (unsigned)f2bf(ac[kt][2] * inv) | ((unsigned)f2bf(ac[kt][3] * inv) << 16);
        u.z = (unsigned)f2bf(ac[kt][4] * inv) | ((unsigned)f2bf(ac[kt][5] * inv) << 16);
        u.w = (unsigned)f2bf(ac[kt][6] * inv) | ((unsigned)f2bf(ac[kt][7] * inv) << 16);
        am[kt] = __builtin_bit_cast(short8, u);
    }

    const int cl = lane & 15;
    const int g4 = (lane >> 4) << 2;

    f32x4 acc8[2][4];   // [si][nt2], col-tile Q -> acc8[Q>>2][Q&3]

    // col-tile Q: B-fragments straight from global (L2-hot, 1 KB coalesced per
    // wave-load). Tile base Q*4096 u16; fragment + kt*512 + lane*8.
    #pragma unroll
    for (int Q = 0; Q < 8; ++Q) {
        const u16* bh_base = Wph + Q * 4096 + lane * 8;
        const u16* bl_base = Wpl + Q * 4096 + lane * 8;
        f32x4 acc_ = {0.f, 0.f, 0.f, 0.f};
        #pragma unroll
        for (int kt = 0; kt < 8; ++kt) {
            const short8 bh_ = *(const short8*)(bh_base + kt * 512);
            const short8 bl_ = *(const short8*)(bl_base + kt * 512);
            if (kt < 4) {
                acc_ = __builtin_amdgcn_mfma_f32_16x16x32_bf16(am[kt], bh_, acc_, 0, 0, 0);
                acc_ = __builtin_amdgcn_mfma_f32_16x16x32_bf16(am[kt], bl_, acc_, 0, 0, 0);
            } else {
                acc_ = __builtin_amdgcn_mfma_f32_16x16x32_bf16(ah[kt - 4], bh_, acc_, 0, 0, 0);
                acc_ = __builtin_amdgcn_mfma_f32_16x16x32_bf16(ah[kt - 4], bl_, acc_, 0, 0, 0);
                acc_ = __builtin_amdgcn_mfma_f32_16x16x32_bf16(al[kt - 4], bh_, acc_, 0, 0, 0);
            }
        }
        acc8[Q >> 2][Q & 3] = acc_;
    }

    char* bounceB = (char*)ldsB + wv * 2048;  // per-wave 2 KB (private)

    if (rowdot) {
        float wsum[4] = {0.f, 0.f, 0.f, 0.f};
        #pragma unroll
        for (int si = 0; si < 2; ++si) {
            #pragma unroll
            for (int nt2 = 0; nt2 < 4; ++nt2) {
                const int col = (si * 4 + nt2) * 16 + cl;
                const float bv = bias[col];
                const float wroc = Wro[col];
                #pragma unroll
                for (int r = 0; r < 4; ++r) {
                    const float v = fmaxf(acc8[si][nt2][r] + bv, 0.f);
                    wsum[r] = fmaf(v, wroc, wsum[r]);
                }
            }
        }
        #pragma unroll
        for (int r = 0; r < 4; ++r) {
            float tsum = wsum[r];
            tsum += __shfl_down(tsum, 8, 64);
            tsum += __shfl_down(tsum, 4, 64);
            tsum += __shfl_down(tsum, 2, 64);
            tsum += __shfl_down(tsum, 1, 64);
            const int lg = m0 + g4 + r;
            if (cl == 0 && lg < N_NODES) {
                rowdot[perm[lg]] = tsum;   // plain store, row owned by this wave
            }
        }
    } else {
        #pragma unroll
        for (int si = 0; si < 2; ++si) {
            // pass 1: bias+relu+split; hi plane -> swizzled LDS, lo bits -> regs
            asm volatile("s_waitcnt lgkmcnt(0)" ::: "memory");  // prior readback done
            unsigned int lo_pack[8];
            #pragma unroll
            for (int nt2 = 0; nt2 < 4; ++nt2) {
                const int col = (si * 4 + nt2) * 16 + cl;
                const float bv = bias[col];
                #pragma unroll
                for (int r = 0; r < 4; ++r) {
                    const int rr = g4 + r;
                    const float v = fmaxf(acc8[si][nt2][r] + bv, 0.f);
                    unsigned int h16, l16;
                    split2(v, h16, l16);
                    const int boff = (rr * 128 + (nt2 * 16 + cl) * 2) ^ ((rr & 7) << 4);
                    *(u16*)(bounceB + boff) = (u16)h16;
                    if (r & 1) lo_pack[nt2 * 2 + (r >> 1)] |= l16 << 16;
                    else       lo_pack[nt2 * 2 + (r >> 1)]  = l16;
                }
            }
            asm volatile("s_waitcnt lgkmcnt(0)" ::: "memory");
            // hi readback: contiguous 16 B/lane, 128 B per (permuted) row
            #pragma unroll
            for (int j = 0; j < 2; ++j) {
                const int rr = j * 8 + (lane >> 3);
                const int blk = lane & 7;
                const uint4 vv = *(const uint4*)(bounceB + rr * 128 + ((blk ^ (rr & 7)) << 4));
                const int lg = m0 + rr;
                if (lg < N_NODES)
                    *(uint4*)(OHhi + (size_t)perm[lg] * D + si * 64 + blk * 8) = vv;
            }
            asm volatile("s_waitcnt lgkmcnt(0)" ::: "memory");
            // pass 2: lo plane through the same bounce tile
            #pragma unroll
            for (int nt2 = 0; nt2 < 4; ++nt2) {
                #pragma unroll
                for (int r = 0; r < 4; ++r) {
                    const int rr = g4 + r;
                    const unsigned int l16 = (lo_pack[nt2 * 2 + (r >> 1)] >> ((r & 1) * 16)) & 0xffffu;
                    const int boff = (rr * 128 + (nt2 * 16 + cl) * 2) ^ ((rr & 7) << 4);
                    *(u16*)(bounceB + boff) = (u16)l16;
                }
            }
            asm volatile("s_waitcnt lgkmcnt(0)" ::: "memory");
            #pragma unroll
            for (int j = 0; j < 2; ++j) {
                const int rr = j * 8 + (lane >> 3);
                const int blk = lane & 7;
                const uint4 vv = *(const uint4*)(bounceB + rr * 128 + ((blk ^ (rr & 7)) << 4));
                const int lg = m0 + rr;
                if (lg < N_NODES)
                    *(uint4*)(OHlo + (size_t)perm[lg] * D + si * 64 + blk * 8) = vv;
            }
        }
    }
}

// ---------------- final: per-graph sum of rowdot + sigmoid (batch sorted) ----------------
__global__ __launch_bounds__(64) void final_kernel(const float* __restrict__ rowdot,
                                                   const int* __restrict__ batch,
                                                   const float* __restrict__ bro,
                                                   float* __restrict__ out) {
    const int g = blockIdx.x;
    const int t = threadIdx.x;
    int lo = 0, hi = N_NODES;
    while (lo < hi) { int mid = (lo + hi) >> 1; if (batch[mid] < g) lo = mid + 1; else hi = mid; }
    int lo2 = lo, hi2 = N_NODES;
    while (lo2 < hi2) { int mid = (lo2 + hi2) >> 1; if (batch[mid] < g + 1) lo2 = mid + 1; else hi2 = mid; }

    float acc = 0.0f;
    for (int i = lo + t; i < lo2; i += 64) acc += rowdot[i];
    #pragma unroll
    for (int off = 32; off > 0; off >>= 1) acc += __shfl_down(acc, off, 64);
    if (t == 0) out[g] = 1.0f / (1.0f + expf(-(acc + bro[0])));
}

extern "C" void kernel_launch(void* const* d_in, const int* in_sizes, int n_in,
                              void* d_out, int out_size, void* d_ws, size_t ws_size,
                              hipStream_t stream) {
    const float* x     = (const float*)d_in[0];
    const int*   ei    = (const int*)d_in[1];
    const int*   batch = (const int*)d_in[2];
    const int*   src   = ei;
    const int*   dst   = ei + N_EDGES;
    const float* Wl[3] = {(const float*)d_in[3], (const float*)d_in[6], (const float*)d_in[9]};
    const float* Wr[3] = {(const float*)d_in[4], (const float*)d_in[7], (const float*)d_in[10]};
    const float* bs[3] = {(const float*)d_in[5], (const float*)d_in[8], (const float*)d_in[11]};
    const float* Wro   = (const float*)d_in[12];
    const float* bro   = (const float*)d_in[13];
    float* out = (float*)d_out;

    const size_t ND = (size_t)N_NODES * D;
    char* ws = (char*)d_ws;
    u16* Ahi = (u16*)ws;                           // ND u16 (ping-pong plane A)
    u16* Alo = Ahi + ND;                           // ND u16
    u16* Bhi = Alo + ND;                           // ND u16 (ping-pong plane B)
    u16* Blo = Bhi + ND;                           // ND u16
    u16* Wph = Blo + ND;                           // 3*32768 u16
    u16* Wpl = Wph + 3 * 32768;                    // 3*32768 u16
    int* deg      = (int*)(Wpl + 3 * 32768);       // N (deg+fill+bintot zeroed together)
    int* fill     = deg + N_NODES;                 // N
    int* bintot   = fill + N_NODES;                // DBINS
    float* rowdot = (float*)(bintot + DBINS);      // N
    int* excl     = (int*)(rowdot + N_NODES);      // N
    int* blocksum = excl + N_NODES;                // 128
    int* rowptr   = blocksum + 128;                // N+1
    int* csr_src  = rowptr + N_NODES + 1;          // E
    int* histT    = csr_src + N_EDGES;             // DBINS*DNB2
    int* perm     = histT + DBINS * DNB2;          // N

    const int EB      = (N_EDGES + 255) / 256;               // 2344
    const int NB      = (N_NODES + 255) / 256;               // 391
    const int NBZ     = (2 * N_NODES + DBINS + 255) / 256;
    const int EPB     = ((E4 + 255) / 256) * NPART;          // partitioned (fill)
    const int PREP_B  = SPLIT_B + 48;                        // split-x + wprep
    const int GEMM_B  = (N_NODES + 127) / 128;               // 782

    // ---- CSR build + prep + degree sort (launch-fused, 5 kernels) ----
    zero_i_kernel<<<NBZ, 256, 0, stream>>>(deg, 2 * N_NODES + DBINS);
    histprep_kernel<<<EB + PREP_B, 256, 0, stream>>>(dst, deg, x, Ahi, Alo,
                                                     Wl[0], Wr[0], Wl[1], Wr[1],
                                                     Wl[2], Wr[2], Wph, Wpl, EB);
    scan1d_kernel<<<SCAN_NBC, SCAN_BS, 0, stream>>>(deg, excl, blocksum, histT, bintot);
    scan3d_kernel<<<NB + DBINS, 256, 0, stream>>>(excl, blocksum, rowptr, bintot, histT, NB);
    filld_kernel<<<EPB + DNB2, 256, 0, stream>>>(src, dst, rowptr, fill, csr_src,
                                                 deg, histT, perm, EPB);

    // ---- 3 fused agg+GEMM layers, ping-pong A<->B; layer 3 -> rowdot ----
    // l=0: A -> B; l=1: B -> A; l=2: A -> rowdot
    gemm_kernel<<<GEMM_B, 512, 0, stream>>>(Ahi, Alo, rowptr, csr_src, perm,
                                            Wph, Wpl, bs[0],
                                            Bhi, Blo, Wro, (float*)nullptr);
    gemm_kernel<<<GEMM_B, 512, 0, stream>>>(Bhi, Blo, rowptr, csr_src, perm,
                                            Wph + 32768, Wpl + 32768, bs[1],
                                            Ahi, Alo, Wro, (float*)nullptr);
    gemm_kernel<<<GEMM_B, 512, 0, stream>>>(Ahi, Alo, rowptr, csr_src, perm,
                                            Wph + 2 * 32768, Wpl + 2 * 32768, bs[2],
                                            Bhi, Blo, Wro, rowdot);

    // ---- per-graph sum + sigmoid ----
    final_kernel<<<N_GRAPHS, 64, 0, stream>>>(rowdot, batch, bro, out);
}

// Round 16
// 330.521 us; speedup vs baseline: 1.1984x; 1.1984x over previous
//
#include <hip/hip_runtime.h>
#include <math.h>

#define N_NODES 100000
#define N_EDGES 600000
#define N_GRAPHS 512
#define D 128
#define SCAN_BS 1024
#define SCAN_NBC ((N_NODES + SCAN_BS - 1) / SCAN_BS)   // 98
#define NPART 8
#define PART_SZ (N_NODES / NPART)                      // 12500
#define E4 (N_EDGES / 4)                               // 150000
#define SPLIT_B 12500                                  // (N*D/4)/256
#define DBINS 64
#define DNB2 SCAN_NBC                                  // 98 chunks of 1024 nodes

typedef unsigned short u16;
typedef __attribute__((ext_vector_type(8))) short short8;
typedef __attribute__((ext_vector_type(4))) float f32x4;

__device__ __forceinline__ u16 f2bf(float f) {
    unsigned int u = __float_as_uint(f);
    u += 0x7FFFu + ((u >> 16) & 1u);
    return (u16)(u >> 16);
}
__device__ __forceinline__ float bf2f(u16 h) {
    return __uint_as_float(((unsigned int)h) << 16);
}
// fp32 -> (hi bf16 bits, lo bf16 bits) in low 16 of each
__device__ __forceinline__ void split2(float f, unsigned int& h16, unsigned int& l16) {
    unsigned int u = __float_as_uint(f);
    unsigned int hb = (u + (0x7FFFu + ((u >> 16) & 1u))) & 0xffff0000u;
    float lo = f - __uint_as_float(hb);
    unsigned int ul = __float_as_uint(lo);
    h16 = hb >> 16;
    l16 = (ul + (0x7FFFu + ((ul >> 16) & 1u))) >> 16;
}

// async global->LDS, 16 B per lane. LDS dest must be wave-uniform base + lane*16.
typedef __attribute__((address_space(1))) const unsigned int gas_u32;
typedef __attribute__((address_space(3))) unsigned int las_u32;
__device__ __forceinline__ void gload16(const void* g, void* l) {
    __builtin_amdgcn_global_load_lds((gas_u32*)g, (las_u32*)l, 16, 0, 0);
}

// ---------------- zero helper ----------------
__global__ __launch_bounds__(256) void zero_i_kernel(int* __restrict__ p, int n) {
    int i = blockIdx.x * 256 + threadIdx.x;
    if (i < n) p[i] = 0;
}

// ---------------- R13 launch fusion ----------------
// histprep = hist U prep; scan1d = scan1 + degree-histogram; scan3d = scan3 U
// per-bin scan; filld = fill U dscatter. Sort binned in 98 chunks of 1024.
// R15 post-mortem: barrier-free direct-L2 B-reads REGRESSED (65->77.7 us) --
// L2-hit latency (~200 cy) on the MFMA path costs more than the 16 barriers
// it saved; LDS staging (ds_read_b128 ~12 cy, deep pipelining) earns its
// barriers. This file is the R13 best-known configuration, reverted.

// ---- histprep: [0,EB) edge histogram; [EB,..) split-x + pack W ----
__global__ __launch_bounds__(256) void histprep_kernel(const int* __restrict__ dst,
                                                       int* __restrict__ deg,
                                                       const float* __restrict__ x,
                                                       u16* __restrict__ Hhi,
                                                       u16* __restrict__ Hlo,
                                                       const float* __restrict__ Wl1, const float* __restrict__ Wr1,
                                                       const float* __restrict__ Wl2, const float* __restrict__ Wr2,
                                                       const float* __restrict__ Wl3, const float* __restrict__ Wr3,
                                                       u16* __restrict__ wph, u16* __restrict__ wpl,
                                                       int EB) {
    if ((int)blockIdx.x < EB) {
        int e = blockIdx.x * 256 + threadIdx.x;
        if (e < N_EDGES) atomicAdd(&deg[dst[e]], 1);
        return;
    }
    const int pbid = blockIdx.x - EB;
    if (pbid < SPLIT_B) {
        const int i = pbid * 256 + threadIdx.x;   // 4 elems/thread
        const float4 v = ((const float4*)x)[i];
        unsigned int h0, l0, h1, l1, h2, l2, h3, l3;
        split2(v.x, h0, l0); split2(v.y, h1, l1);
        split2(v.z, h2, l2); split2(v.w, h3, l3);
        uint2 oh, ol;
        oh.x = h0 | (h1 << 16); oh.y = h2 | (h3 << 16);
        ol.x = l0 | (l1 << 16); ol.y = l2 | (l3 << 16);
        ((uint2*)Hhi)[i] = oh;
        ((uint2*)Hlo)[i] = ol;
    } else {
        const int b = (pbid - SPLIT_B) * 4 + (threadIdx.x >> 6);  // 0..191
        const int lane = threadIdx.x & 63;
        const int layer = b >> 6;
        const int t = b & 63;
        const float* Wl = (layer == 0) ? Wl1 : (layer == 1) ? Wl2 : Wl3;
        const float* Wr = (layer == 0) ? Wr1 : (layer == 1) ? Wr2 : Wr3;
        const int nt = t >> 3, kt = t & 7;
        const int n = nt * 16 + (lane & 15);
        const int k0 = kt * 32 + (lane >> 4) * 8;
        const size_t base = (size_t)layer * 32768 + (size_t)(t * 64 + lane) * 8;
        #pragma unroll
        for (int j = 0; j < 8; ++j) {
            const int k = k0 + j;
            const float w = (k < 128) ? Wl[k * 128 + n] : Wr[(k - 128) * 128 + n];
            const u16 h = f2bf(w);
            wph[base + j] = h;
            wpl[base + j] = f2bf(w - bf2f(h));
        }
    }
}

// ---- scan1d: node-degree block scan (rowptr part 1) + degree histogram ----
__global__ __launch_bounds__(1024) void scan1d_kernel(const int* __restrict__ deg,
                                                      int* __restrict__ excl,
                                                      int* __restrict__ blocksum,
                                                      int* __restrict__ histT,
                                                      int* __restrict__ bintot) {
    __shared__ int buf[2][SCAN_BS];
    __shared__ int h[DBINS];
    const int t = threadIdx.x;
    const int gid = blockIdx.x * SCAN_BS + t;
    int v = (gid < N_NODES) ? deg[gid] : 0;
    if (t < DBINS) h[t] = 0;
    buf[0][t] = v;
    __syncthreads();
    if (gid < N_NODES) atomicAdd(&h[63 - min(v, 63)], 1);   // descending-degree bin
    int pi = 0;
    for (int off = 1; off < SCAN_BS; off <<= 1) {
        int val = buf[pi][t];
        if (t >= off) val += buf[pi][t - off];
        buf[pi ^ 1][t] = val;
        pi ^= 1;
        __syncthreads();
    }
    int incl = buf[pi][t];
    if (gid < N_NODES) excl[gid] = incl - v;
    if (t == SCAN_BS - 1) blocksum[blockIdx.x] = incl;
    if (t < DBINS) {
        histT[t * DNB2 + blockIdx.x] = h[t];
        if (h[t] > 0) atomicAdd(&bintot[t], h[t]);
    }
}

// ---- scan3d: [0,NB) rowptr finalize; [NB,NB+64) per-bin offset scan ----
__global__ __launch_bounds__(256) void scan3d_kernel(const int* __restrict__ excl,
                                                     const int* __restrict__ blocksum,
                                                     int* __restrict__ rowptr,
                                                     const int* __restrict__ bintot,
                                                     int* __restrict__ histT,
                                                     int NB) {
    const int t = threadIdx.x;
    if ((int)blockIdx.x < NB) {
        __shared__ int buf[2][128];
        if (t < 128) buf[0][t] = (t < SCAN_NBC) ? blocksum[t] : 0;
        __syncthreads();
        int pi = 0;
        for (int off = 1; off < 128; off <<= 1) {
            if (t < 128) {
                int val = buf[pi][t];
                if (t >= off) val += buf[pi][t - off];
                buf[pi ^ 1][t] = val;
            }
            pi ^= 1;
            __syncthreads();
        }
        const int i = blockIdx.x * 256 + t;
        if (i < N_NODES) {
            const int j = i / SCAN_BS;
            const int pref = (j == 0) ? 0 : buf[pi][j - 1];
            rowptr[i] = excl[i] + pref;
        }
        if (i == 0) rowptr[N_NODES] = N_EDGES;
    } else {
        // per-bin exclusive scan of histT[b][0..DNB2) + global bin base
        __shared__ int buf[2][128];
        __shared__ int base;
        const int b = blockIdx.x - NB;
        if (t == 0) {
            int s = 0;
            for (int j = 0; j < b; ++j) s += bintot[j];
            base = s;
        }
        int v = 0;
        if (t < 128) {
            v = (t < DNB2) ? histT[b * DNB2 + t] : 0;
            buf[0][t] = v;
        }
        __syncthreads();
        int pi = 0;
        for (int off = 1; off < 128; off <<= 1) {
            if (t < 128) {
                int val = buf[pi][t];
                if (t >= off) val += buf[pi][t - off];
                buf[pi ^ 1][t] = val;
            }
            pi ^= 1;
            __syncthreads();
        }
        if (t < DNB2) histT[b * DNB2 + t] = base + buf[pi][t] - v;
    }
}

// ---- filld: [0,EPB) CSR fill (dst-range partitioned, R2 scatter-locality
// win); [EPB,EPB+DNB2) degree-sort scatter (1024 nodes/block) ----
__global__ __launch_bounds__(256) void filld_kernel(const int* __restrict__ src,
                                                    const int* __restrict__ dst,
                                                    const int* __restrict__ rowptr,
                                                    int* __restrict__ fill,
                                                    int* __restrict__ csr_src,
                                                    const int* __restrict__ deg,
                                                    const int* __restrict__ offs,
                                                    int* __restrict__ perm,
                                                    int EPB) {
    if ((int)blockIdx.x < EPB) {
        const int lo = (blockIdx.x & (NPART - 1)) * PART_SZ;
        const int i4 = (blockIdx.x >> 3) * 256 + threadIdx.x;
        if (i4 >= E4) return;
        const int4 d4 = ((const int4*)dst)[i4];
        const int4 s4 = ((const int4*)src)[i4];
        if ((unsigned)(d4.x - lo) < (unsigned)PART_SZ) {
            int pos = rowptr[d4.x] + atomicAdd(&fill[d4.x], 1);
            csr_src[pos] = s4.x;
        }
        if ((unsigned)(d4.y - lo) < (unsigned)PART_SZ) {
            int pos = rowptr[d4.y] + atomicAdd(&fill[d4.y], 1);
            csr_src[pos] = s4.y;
        }
        if ((unsigned)(d4.z - lo) < (unsigned)PART_SZ) {
            int pos = rowptr[d4.z] + atomicAdd(&fill[d4.z], 1);
            csr_src[pos] = s4.z;
        }
        if ((unsigned)(d4.w - lo) < (unsigned)PART_SZ) {
            int pos = rowptr[d4.w] + atomicAdd(&fill[d4.w], 1);
            csr_src[pos] = s4.w;
        }
    } else {
        __shared__ int c[DBINS];
        const int t = threadIdx.x;
        const int chunk = blockIdx.x - EPB;
        if (t < DBINS) c[t] = 0;
        __syncthreads();
        #pragma unroll
        for (int k = 0; k < 4; ++k) {
            const int i = chunk * 1024 + k * 256 + t;
            if (i < N_NODES) {
                const int b = 63 - min(deg[i], 63);
                const int r = atomicAdd(&c[b], 1);
                perm[offs[b * DNB2 + chunk] + r] = i;
            }
        }
    }
}

// ---------------- FUSED agg + MFMA GEMM (degree-sorted rows) ----------------
// h' = relu([mean_nbr(INhi) | IN] @ [Wl;Wr] + b), OUT != IN (ping-pong).
// Rows processed in perm order (descending degree = LPT). All loads/stores for
// a logical slot lg use physical row perm[lg]; per-row math identical.
// W pipeline (R10): EIGHT 16 KB stages through a 2x16 KB LDS dbuf via
// global_load_lds, raw s_barrier + counted vmcnt (vmcnt(2) steady state,
// vmcnt(0) at the ends); epilogue bounce overlays bufA after the pre-C7
// drain. LDS 32 KB.
// Layer 3: rowdot[perm[lg]] = sum_col relu(.)*Wro[col] (no h' write).
__global__ __launch_bounds__(512, 4) void gemm_kernel(const u16* __restrict__ INhi,
                                                      const u16* __restrict__ INlo,
                                                      const int* __restrict__ rowptr,
                                                      const int* __restrict__ csr_src,
                                                      const int* __restrict__ perm,
                                                      const u16* __restrict__ Wph,
                                                      const u16* __restrict__ Wpl,
                                                      const float* __restrict__ bias,
                                                      u16* __restrict__ OHhi,
                                                      u16* __restrict__ OHlo,
                                                      const float* __restrict__ Wro,
                                                      float* rowdot) {
    __shared__ uint4 ldsAll[2048];   // 32 KB: W dbuf A=[0:1024) B=[1024:2048); bounce overlays A post-C6
    const int t = threadIdx.x;
    const int lane = t & 63;
    const int wv = t >> 6;
    const int m0 = blockIdx.x * 128 + wv * 16;
    const int gid = m0 + (lane & 15);            // logical row slot
    const int ko = (lane >> 4) * 8;

    int prow = 0, beg = 0, deg = 0;
    if (gid < N_NODES) {
        prow = perm[gid];
        beg = rowptr[prow];
        deg = rowptr[prow + 1] - beg;
    }
    const int rm = prow;                         // 0 for invalid slots (safe)

    // stage Q = col-tile Q (hi 8 KB + lo 8 KB) into buffer B. 2 gloads/thread.
#define STAGE_W(Q, B) do {                                                      \
        const uint4* gh_ = (const uint4*)Wph + (Q) * 512;                       \
        const uint4* gl_ = (const uint4*)Wpl + (Q) * 512;                       \
        gload16(gh_ + t, (void*)&ldsAll[(B) * 1024 + wv * 64]);                 \
        gload16(gl_ + t, (void*)&ldsAll[(B) * 1024 + 512 + wv * 64]);           \
    } while (0)

    // W stages 0 and 1 issued FIRST: their HBM fetch overlaps the gather.
    STAGE_W(0, 0);
    __builtin_amdgcn_sched_barrier(0);
    STAGE_W(1, 1);
    __builtin_amdgcn_sched_barrier(0);

    // root A fragments: latency hides under the gather
    short8 ah[4], al[4];
    #pragma unroll
    for (int kt = 0; kt < 4; ++kt) {
        ah[kt] = *(const short8*)(INhi + (size_t)rm * D + kt * 32 + ko);
        al[kt] = *(const short8*)(INlo + (size_t)rm * D + kt * 32 + ko);
    }

    // ---- fused aggregation (R6 form): mean of neighbor rows, 32 cols/lane ----
    float ac[4][8];
    #pragma unroll
    for (int kt = 0; kt < 4; ++kt) {
        #pragma unroll
        for (int j = 0; j < 8; ++j) ac[kt][j] = 0.f;
    }
    int s_cur = (deg > 0) ? csr_src[beg] : 0;
    for (int n = 0; __any(n < deg); ++n) {
        const bool act = n < deg;
        const int s_nxt = (n + 1 < deg) ? csr_src[beg + n + 1] : 0;
        if (act) {
            const size_t rb = (size_t)s_cur * D + ko;
            #pragma unroll
            for (int kt = 0; kt < 4; ++kt) {
                const uint4 v = *(const uint4*)(INhi + rb + kt * 32);
                ac[kt][0] += __uint_as_float(v.x << 16);
                ac[kt][1] += __uint_as_float(v.x & 0xffff0000u);
                ac[kt][2] += __uint_as_float(v.y << 16);
                ac[kt][3] += __uint_as_float(v.y & 0xffff0000u);
                ac[kt][4] += __uint_as_float(v.z << 16);
                ac[kt][5] += __uint_as_float(v.z & 0xffff0000u);
                ac[kt][6] += __uint_as_float(v.w << 16);
                ac[kt][7] += __uint_as_float(v.w & 0xffff0000u);
            }
        }
        s_cur = s_nxt;
    }
    const float inv = 1.0f / (float)max(deg, 1);
    short8 am[4];
    #pragma unroll
    for (int kt = 0; kt < 4; ++kt) {
        uint4 u;
        u.x = (unsigned)f2bf(ac[kt][0] * inv) | ((unsigned)f2bf(ac[kt][1] * inv) << 16);
        u.y = (unsigned)f2bf(ac[kt][2] * inv) | ((unsigned)f2bf(ac[kt][3] * inv) << 16);
        u.z = (unsigned)f2bf(ac[kt][4] * inv) | ((unsigned)f2bf(ac[kt][5] * inv) << 16);
        u.w = (unsigned)f2bf(ac[kt][6] * inv) | ((unsigned)f2bf(ac[kt][7] * inv) << 16);
        am[kt] = __builtin_bit_cast(short8, u);
    }
    __builtin_amdgcn_sched_barrier(0);

    const int cl = lane & 15;
    const int g4 = (lane >> 4) << 2;

    f32x4 acc8[2][4];   // [si][nt2], col-tile Q -> acc8[Q>>2][Q&3]

    // compute col-tile Q from buffer B: 8 kt x 5-MFMA hi/lo pattern
#define COMPUTE_S(Q, B) do {                                                    \
        const u16* bufU_ = (const u16*)(ldsAll + (B) * 1024);                   \
        f32x4 acc_ = {0.f, 0.f, 0.f, 0.f};                                      \
        _Pragma("unroll")                                                       \
        for (int kt_ = 0; kt_ < 8; ++kt_) {                                     \
            const int fo_ = kt_ * 512 + lane * 8;                               \
            const short8 bh_ = *(const short8*)(bufU_ + fo_);                   \
            const short8 bl_ = *(const short8*)(bufU_ + 4096 + fo_);            \
            if (kt_ < 4) {                                                      \
                acc_ = __builtin_amdgcn_mfma_f32_16x16x32_bf16(am[kt_], bh_, acc_, 0, 0, 0); \
                acc_ = __builtin_amdgcn_mfma_f32_16x16x32_bf16(am[kt_], bl_, acc_, 0, 0, 0); \
            } else {                                                            \
                acc_ = __builtin_amdgcn_mfma_f32_16x16x32_bf16(ah[kt_ - 4], bh_, acc_, 0, 0, 0); \
                acc_ = __builtin_amdgcn_mfma_f32_16x16x32_bf16(ah[kt_ - 4], bl_, acc_, 0, 0, 0); \
                acc_ = __builtin_amdgcn_mfma_f32_16x16x32_bf16(al[kt_ - 4], bh_, acc_, 0, 0, 0); \
            }                                                                   \
        }                                                                       \
        acc8[(Q) >> 2][(Q) & 3] = acc_;                                         \
    } while (0)

    asm volatile("s_waitcnt vmcnt(0)" ::: "memory");   // gather + root + L0 + L1 done
    __builtin_amdgcn_s_barrier();                      // buf0+buf1 fully populated
    COMPUTE_S(0, 0);
    __builtin_amdgcn_s_barrier();               // all waves done reading bufA (C0)
    STAGE_W(2, 0);
    __builtin_amdgcn_sched_barrier(0);
    COMPUTE_S(1, 1);                            // no wait: bufB warm since pre-C0 drain
    __builtin_amdgcn_s_barrier();               // all waves done reading bufB (C1)
    STAGE_W(3, 1);
    asm volatile("s_waitcnt vmcnt(2)" ::: "memory");   // L2 done, L3 in flight
    __builtin_amdgcn_s_barrier();
    COMPUTE_S(2, 0);
    __builtin_amdgcn_s_barrier();
    STAGE_W(4, 0);
    asm volatile("s_waitcnt vmcnt(2)" ::: "memory");   // L3 done, L4 in flight
    __builtin_amdgcn_s_barrier();
    COMPUTE_S(3, 1);
    __builtin_amdgcn_s_barrier();
    STAGE_W(5, 1);
    asm volatile("s_waitcnt vmcnt(2)" ::: "memory");   // L4 done, L5 in flight
    __builtin_amdgcn_s_barrier();
    COMPUTE_S(4, 0);
    __builtin_amdgcn_s_barrier();
    STAGE_W(6, 0);
    asm volatile("s_waitcnt vmcnt(2)" ::: "memory");   // L5 done, L6 in flight
    __builtin_amdgcn_s_barrier();
    COMPUTE_S(5, 1);
    __builtin_amdgcn_s_barrier();
    STAGE_W(7, 1);
    asm volatile("s_waitcnt vmcnt(2)" ::: "memory");   // L6 done, L7 in flight
    __builtin_amdgcn_s_barrier();
    COMPUTE_S(6, 0);
    asm volatile("s_waitcnt vmcnt(0)" ::: "memory");   // L7 done (had all of C6)
    __builtin_amdgcn_s_barrier();               // all waves past C6 -> bufA free
    COMPUTE_S(7, 1);

    char* bounceB = (char*)ldsAll + wv * 2048;  // per-wave 2 KB, overlays bufA

    if (rowdot) {
        float wsum[4] = {0.f, 0.f, 0.f, 0.f};
        #pragma unroll
        for (int si = 0; si < 2; ++si) {
            #pragma unroll
            for (int nt2 = 0; nt2 < 4; ++nt2) {
                const int col = (si * 4 + nt2) * 16 + cl;
                const float bv = bias[col];
                const float wroc = Wro[col];
                #pragma unroll
                for (int r = 0; r < 4; ++r) {
                    const float v = fmaxf(acc8[si][nt2][r] + bv, 0.f);
                    wsum[r] = fmaf(v, wroc, wsum[r]);
                }
            }
        }
        #pragma unroll
        for (int r = 0; r < 4; ++r) {
            float tsum = wsum[r];
            tsum += __shfl_down(tsum, 8, 64);
            tsum += __shfl_down(tsum, 4, 64);
            tsum += __shfl_down(tsum, 2, 64);
            tsum += __shfl_down(tsum, 1, 64);
            const int lg = m0 + g4 + r;
            if (cl == 0 && lg < N_NODES) {
                rowdot[perm[lg]] = tsum;   // plain store, row owned by this wave
            }
        }
    } else {
        #pragma unroll
        for (int si = 0; si < 2; ++si) {
            // pass 1: bias+relu+split; hi plane -> swizzled LDS, lo bits -> regs
            asm volatile("s_waitcnt lgkmcnt(0)" ::: "memory");  // prior readback done
            unsigned int lo_pack[8];
            #pragma unroll
            for (int nt2 = 0; nt2 < 4; ++nt2) {
                const int col = (si * 4 + nt2) * 16 + cl;
                const float bv = bias[col];
                #pragma unroll
                for (int r = 0; r < 4; ++r) {
                    const int rr = g4 + r;
                    const float v = fmaxf(acc8[si][nt2][r] + bv, 0.f);
                    unsigned int h16, l16;
                    split2(v, h16, l16);
                    const int boff = (rr * 128 + (nt2 * 16 + cl) * 2) ^ ((rr & 7) << 4);
                    *(u16*)(bounceB + boff) = (u16)h16;
                    if (r & 1) lo_pack[nt2 * 2 + (r >> 1)] |= l16 << 16;
                    else       lo_pack[nt2 * 2 + (r >> 1)]  = l16;
                }
            }
            asm volatile("s_waitcnt lgkmcnt(0)" ::: "memory");
            // hi readback: contiguous 16 B/lane, 128 B per (permuted) row
            #pragma unroll
            for (int j = 0; j < 2; ++j) {
                const int rr = j * 8 + (lane >> 3);
                const int blk = lane & 7;
                const uint4 vv = *(const uint4*)(bounceB + rr * 128 + ((blk ^ (rr & 7)) << 4));
                const int lg = m0 + rr;
                if (lg < N_NODES)
                    *(uint4*)(OHhi + (size_t)perm[lg] * D + si * 64 + blk * 8) = vv;
            }
            asm volatile("s_waitcnt lgkmcnt(0)" ::: "memory");
            // pass 2: lo plane through the same bounce tile
            #pragma unroll
            for (int nt2 = 0; nt2 < 4; ++nt2) {
                #pragma unroll
                for (int r = 0; r < 4; ++r) {
                    const int rr = g4 + r;
                    const unsigned int l16 = (lo_pack[nt2 * 2 + (r >> 1)] >> ((r & 1) * 16)) & 0xffffu;
                    const int boff = (rr * 128 + (nt2 * 16 + cl) * 2) ^ ((rr & 7) << 4);
                    *(u16*)(bounceB + boff) = (u16)l16;
                }
            }
            asm volatile("s_waitcnt lgkmcnt(0)" ::: "memory");
            #pragma unroll
            for (int j = 0; j < 2; ++j) {
                const int rr = j * 8 + (lane >> 3);
                const int blk = lane & 7;
                const uint4 vv = *(const uint4*)(bounceB + rr * 128 + ((blk ^ (rr & 7)) << 4));
                const int lg = m0 + rr;
                if (lg < N_NODES)
                    *(uint4*)(OHlo + (size_t)perm[lg] * D + si * 64 + blk * 8) = vv;
            }
        }
    }
#undef STAGE_W
#undef COMPUTE_S
}

// ---------------- final: per-graph sum of rowdot + sigmoid (batch sorted) ----------------
__global__ __launch_bounds__(64) void final_kernel(const float* __restrict__ rowdot,
                                                   const int* __restrict__ batch,
                                                   const float* __restrict__ bro,
                                                   float* __restrict__ out) {
    const int g = blockIdx.x;
    const int t = threadIdx.x;
    int lo = 0, hi = N_NODES;
    while (lo < hi) { int mid = (lo + hi) >> 1; if (batch[mid] < g) lo = mid + 1; else hi = mid; }
    int lo2 = lo, hi2 = N_NODES;
    while (lo2 < hi2) { int mid = (lo2 + hi2) >> 1; if (batch[mid] < g + 1) lo2 = mid + 1; else hi2 = mid; }

    float acc = 0.0f;
    for (int i = lo + t; i < lo2; i += 64) acc += rowdot[i];
    #pragma unroll
    for (int off = 32; off > 0; off >>= 1) acc += __shfl_down(acc, off, 64);
    if (t == 0) out[g] = 1.0f / (1.0f + expf(-(acc + bro[0])));
}

extern "C" void kernel_launch(void* const* d_in, const int* in_sizes, int n_in,
                              void* d_out, int out_size, void* d_ws, size_t ws_size,
                              hipStream_t stream) {
    const float* x     = (const float*)d_in[0];
    const int*   ei    = (const int*)d_in[1];
    const int*   batch = (const int*)d_in[2];
    const int*   src   = ei;
    const int*   dst   = ei + N_EDGES;
    const float* Wl[3] = {(const float*)d_in[3], (const float*)d_in[6], (const float*)d_in[9]};
    const float* Wr[3] = {(const float*)d_in[4], (const float*)d_in[7], (const float*)d_in[10]};
    const float* bs[3] = {(const float*)d_in[5], (const float*)d_in[8], (const float*)d_in[11]};
    const float* Wro   = (const float*)d_in[12];
    const float* bro   = (const float*)d_in[13];
    float* out = (float*)d_out;

    const size_t ND = (size_t)N_NODES * D;
    char* ws = (char*)d_ws;
    u16* Ahi = (u16*)ws;                           // ND u16 (ping-pong plane A)
    u16* Alo = Ahi + ND;                           // ND u16
    u16* Bhi = Alo + ND;                           // ND u16 (ping-pong plane B)
    u16* Blo = Bhi + ND;                           // ND u16
    u16* Wph = Blo + ND;                           // 3*32768 u16
    u16* Wpl = Wph + 3 * 32768;                    // 3*32768 u16
    int* deg      = (int*)(Wpl + 3 * 32768);       // N (deg+fill+bintot zeroed together)
    int* fill     = deg + N_NODES;                 // N
    int* bintot   = fill + N_NODES;                // DBINS
    float* rowdot = (float*)(bintot + DBINS);      // N
    int* excl     = (int*)(rowdot + N_NODES);      // N
    int* blocksum = excl + N_NODES;                // 128
    int* rowptr   = blocksum + 128;                // N+1
    int* csr_src  = rowptr + N_NODES + 1;          // E
    int* histT    = csr_src + N_EDGES;             // DBINS*DNB2
    int* perm     = histT + DBINS * DNB2;          // N

    const int EB      = (N_EDGES + 255) / 256;               // 2344
    const int NB      = (N_NODES + 255) / 256;               // 391
    const int NBZ     = (2 * N_NODES + DBINS + 255) / 256;
    const int EPB     = ((E4 + 255) / 256) * NPART;          // partitioned (fill)
    const int PREP_B  = SPLIT_B + 48;                        // split-x + wprep
    const int GEMM_B  = (N_NODES + 127) / 128;               // 782

    // ---- CSR build + prep + degree sort (launch-fused, 5 kernels) ----
    zero_i_kernel<<<NBZ, 256, 0, stream>>>(deg, 2 * N_NODES + DBINS);
    histprep_kernel<<<EB + PREP_B, 256, 0, stream>>>(dst, deg, x, Ahi, Alo,
                                                     Wl[0], Wr[0], Wl[1], Wr[1],
                                                     Wl[2], Wr[2], Wph, Wpl, EB);
    scan1d_kernel<<<SCAN_NBC, SCAN_BS, 0, stream>>>(deg, excl, blocksum, histT, bintot);
    scan3d_kernel<<<NB + DBINS, 256, 0, stream>>>(excl, blocksum, rowptr, bintot, histT, NB);
    filld_kernel<<<EPB + DNB2, 256, 0, stream>>>(src, dst, rowptr, fill, csr_src,
                                                 deg, histT, perm, EPB);

    // ---- 3 fused agg+GEMM layers, ping-pong A<->B; layer 3 -> rowdot ----
    // l=0: A -> B; l=1: B -> A; l=2: A -> rowdot
    gemm_kernel<<<GEMM_B, 512, 0, stream>>>(Ahi, Alo, rowptr, csr_src, perm,
                                            Wph, Wpl, bs[0],
                                            Bhi, Blo, Wro, (float*)nullptr);
    gemm_kernel<<<GEMM_B, 512, 0, stream>>>(Bhi, Blo, rowptr, csr_src, perm,
                                            Wph + 32768, Wpl + 32768, bs[1],
                                            Ahi, Alo, Wro, (float*)nullptr);
    gemm_kernel<<<GEMM_B, 512, 0, stream>>>(Ahi, Alo, rowptr, csr_src, perm,
                                            Wph + 2 * 32768, Wpl + 2 * 32768, bs[2],
                                            Bhi, Blo, Wro, rowdot);

    // ---- per-graph sum + sigmoid ----
    final_kernel<<<N_GRAPHS, 64, 0, stream>>>(rowdot, batch, bro, out);
}